// Round 3
// baseline (136.602 us; speedup 1.0000x reference)
//
#include <hip/hip_runtime.h>
#include <hip/hip_fp16.h>
#include <math.h>

constexpr int N   = 4096;
constexpr int D   = 128;
constexpr int LDK = D + 8;     // bf16 elems per padded tile row (272 B stride)
constexpr int QCAPW = 1024;    // sparse-queue capacity per wave (exp ~258, sigma ~16)

typedef __attribute__((ext_vector_type(8))) short short8;
typedef __attribute__((ext_vector_type(4))) float floatx4;

__device__ inline unsigned short f2bf(float f) {
  unsigned u = __builtin_bit_cast(unsigned, f);
  u = (u + 0x7FFFu + ((u >> 16) & 1u)) >> 16;   // RNE
  return (unsigned short)u;
}

// ws layout: ws[i*256 + bj*8 + k], k: 0=c 1=S1 2=S2 3=dA 4=dB 5=dC 6=T0 7=T1
__global__ __launch_bounds__(256, 2) void logratio_phaseA(
    const float* __restrict__ inputs, const int* __restrict__ labels,
    float* __restrict__ ws,
    float B0, float B1, float B2, float B3,
    float Q0, float Q1, float Q2, float Q3) {

  __shared__ __align__(16) char smem[2 * 128 * LDK * 2];  // 69632 B
  unsigned short* As = (unsigned short*)smem;   // [128][LDK]
  unsigned short* Bs = As + 128 * LDK;
  // post-MFMA reuse of the same region:
  float (*rowacc)[8] = (float (*)[8])smem;                     //  4096 B
  unsigned* queues   = (unsigned*)(smem + 4096);               // 16384 B (4 waves x 1024)
  unsigned* qcnt     = (unsigned*)(smem + 4096 + 16384);       //    16 B

  const int tid = threadIdx.x;
  const int iBase = blockIdx.y * 128;
  const int jBase = blockIdx.x * 128;

  // ---- stage both tiles fp32 -> bf16 ----
#pragma unroll
  for (int p = 0; p < 16; ++p) {
    const int idx = p * 256 + tid;
    const int row = idx >> 5;
    const int cf  = idx & 31;
    const float4 va = *(const float4*)&inputs[(iBase + row) * D + cf * 4];
    uint2 wa;
    wa.x = (unsigned)f2bf(va.x) | ((unsigned)f2bf(va.y) << 16);
    wa.y = (unsigned)f2bf(va.z) | ((unsigned)f2bf(va.w) << 16);
    *(uint2*)&As[row * LDK + cf * 4] = wa;
    const float4 vb = *(const float4*)&inputs[(jBase + row) * D + cf * 4];
    uint2 wb;
    wb.x = (unsigned)f2bf(vb.x) | ((unsigned)f2bf(vb.y) << 16);
    wb.y = (unsigned)f2bf(vb.z) | ((unsigned)f2bf(vb.w) << 16);
    *(uint2*)&Bs[row * LDK + cf * 4] = wb;
  }
  __syncthreads();

  const int w    = tid >> 6;
  const int lane = tid & 63;
  const int lc   = lane & 15;
  const int quad = lane >> 4;

  floatx4 acc[2][8] = {};
  const unsigned short* Abase = As + (w * 32 + lc) * LDK + quad * 8;
  const unsigned short* Bbase = Bs + lc * LDK + quad * 8;

#pragma unroll
  for (int kb = 0; kb < 4; ++kb) {
    short8 af[2], bfr[8];
    af[0] = *(const short8*)(Abase + kb * 32);
    af[1] = *(const short8*)(Abase + 16 * LDK + kb * 32);
#pragma unroll
    for (int tn = 0; tn < 8; ++tn)
      bfr[tn] = *(const short8*)(Bbase + tn * 16 * LDK + kb * 32);
#pragma unroll
    for (int tm = 0; tm < 2; ++tm)
#pragma unroll
      for (int tn = 0; tn < 8; ++tn)
        acc[tm][tn] = __builtin_amdgcn_mfma_f32_16x16x32_bf16(af[tm], bfr[tn], acc[tm][tn], 0, 0, 0);
  }

  int4 labs[8];
#pragma unroll
  for (int tn = 0; tn < 8; ++tn)
    labs[tn] = ((const int4*)labels)[jBase + tn * 16 + lc];

  __syncthreads();               // tile reads done; smem becomes rowacc/queues

  for (int z = tid; z < 128 * 8; z += 256) ((float*)rowacc)[z] = 0.f;
  __syncthreads();

  // ---- pass 1: dense T0/T1 + sparse enqueue (per-wave SGPR-counted queue) ----
  unsigned wq = 0;
  unsigned* wqueue = queues + w * QCAPW;

#pragma unroll
  for (int tm = 0; tm < 2; ++tm) {
#pragma unroll
    for (int reg = 0; reg < 4; ++reg) {
      const int row = w * 32 + tm * 16 + quad * 4 + reg;
      const int gi = iBase + row;
      const int ti = labels[gi * 4];
      float t0 = 0.f, t1 = 0.f;
#pragma unroll
      for (int tn = 0; tn < 8; ++tn) {
        const int col = tn * 16 + lc;
        const float ls = __logf(acc[tm][tn][reg] + 1e-6f);
        t0 += ls;
        t1 = fmaf(ls, ls, t1);
        const int4 L = labs[tn];
        const bool match = (ti == L.x) | (ti == L.y) | (ti == L.z) | (ti == L.w);
        const unsigned long long mk = __ballot(match);
        if (mk) {
          const unsigned pfx = __builtin_amdgcn_mbcnt_hi(
              (unsigned)(mk >> 32), __builtin_amdgcn_mbcnt_lo((unsigned)mk, 0u));
          if (match) {
            const unsigned pos = wq + pfx;
            if (pos < (unsigned)QCAPW)
              wqueue[pos] = ((unsigned)(row * 128 + col) << 16) |
                            (unsigned)__half_as_ushort(__float2half(ls));
          }
          wq += (unsigned)__popcll(mk);
        }
      }
      // reduce t0,t1 across the 16 j-lanes
#pragma unroll
      for (int m = 1; m <= 8; m <<= 1) {
        t0 += __shfl_xor(t0, m, 64);
        t1 += __shfl_xor(t1, m, 64);
      }
      if (lc == 0) { rowacc[row][6] = t0; rowacc[row][7] = t1; }
    }
  }
  if (lane == 0) qcnt[w] = (wq < (unsigned)QCAPW) ? wq : (unsigned)QCAPW;
  __syncthreads();

  // ---- pass 2: sparse corrections (~1030 pairs/block) ----
#pragma unroll 1
  for (int qw = 0; qw < 4; ++qw) {
    const unsigned qn = qcnt[qw];
    const unsigned* qq = queues + qw * QCAPW;
    for (unsigned q = tid; q < qn; q += 256) {
      const unsigned e = qq[q];
      const int idx = (int)(e >> 16);
      const int row = idx >> 7;
      const int col = idx & 127;
      const float ls = __half2float(__ushort_as_half((unsigned short)(e & 0xFFFFu)));
      const int gi = iBase + row, gj = jBase + col;
      const int ti = labels[gi * 4];
      const int4 L = ((const int4*)labels)[gj];
      const bool e0 = (ti == L.x), e1 = (ti == L.y), e2 = (ti == L.z), e3 = (ti == L.w);
      const float g0 = (e3 ? 0.f : 1.f) + ((e3 && !e2) ? 1.f : 0.f) +
                       ((e2 && !e1) ? 1.f : 0.f) + ((e1 && !e0) ? 1.f : 0.f);
      const float gB = (e3 ? (!e2 ? B1 : 0.f) : B0) + ((e2 && !e1) ? B2 : 0.f) + ((e1 && !e0) ? B3 : 0.f);
      const float gQ = (e3 ? (!e2 ? Q1 : 0.f) : Q0) + ((e2 && !e1) ? Q2 : 0.f) + ((e1 && !e0) ? Q3 : 0.f);
      const float fp = (e0 && (gi != gj)) ? 1.f : 0.f;
      const float dg0 = g0 - 1.f, dgB = gB - B0, dgQ = gQ - Q0;
      const float ls2 = ls * ls;
      atomicAdd(&rowacc[row][0], fp);
      atomicAdd(&rowacc[row][1], fp * ls);
      atomicAdd(&rowacc[row][2], fp * ls2);
      atomicAdd(&rowacc[row][3], dg0);
      atomicAdd(&rowacc[row][4], fmaf(dg0, ls, dgB));
      atomicAdd(&rowacc[row][5], fmaf(fmaf(dg0, ls, 2.f * dgB), ls, dgQ));
    }
  }
  __syncthreads();

  // ---- tail: per-block partials, non-atomic (no d_ws zeroing needed) ----
  if (tid < 128) {
    const int gi = iBase + tid;
    float* dst = ws + (size_t)gi * 256 + blockIdx.x * 8;
    *(float4*)dst       = make_float4(rowacc[tid][0], rowacc[tid][1], rowacc[tid][2], rowacc[tid][3]);
    *(float4*)(dst + 4) = make_float4(rowacc[tid][4], rowacc[tid][5], rowacc[tid][6], rowacc[tid][7]);
  }
}

__global__ __launch_bounds__(256) void logratio_phaseB(
    const float* __restrict__ ws, float* __restrict__ out, float B0, float Q0) {
  const int i = blockIdx.x * 256 + threadIdx.x;
  const float4* p = (const float4*)(ws + (size_t)i * 256);
  float4 a0 = make_float4(0.f, 0.f, 0.f, 0.f);
  float4 a1 = make_float4(0.f, 0.f, 0.f, 0.f);
#pragma unroll 8
  for (int b = 0; b < 32; ++b) {
    const float4 x = p[2 * b], y = p[2 * b + 1];
    a0.x += x.x; a0.y += x.y; a0.z += x.z; a0.w += x.w;
    a1.x += y.x; a1.y += y.y; a1.z += y.z; a1.w += y.w;
  }
  const float c = a0.x, S1 = a0.y, S2 = a0.z, dA = a0.w;
  const float dB = a1.x, dC = a1.y, T0 = a1.z, T1 = a1.w;
  const float A  = (float)N + dA;
  const float Bv = T0 + (float)N * B0 + dB;
  const float Cv = T1 + 2.f * B0 * T0 + (float)N * Q0 + dC;
  float v = S2 * A - 2.f * S1 * Bv + c * Cv;
#pragma unroll
  for (int m = 32; m >= 1; m >>= 1) v += __shfl_xor(v, m, 64);
  __shared__ float wsum[4];
  if ((threadIdx.x & 63) == 0) wsum[threadIdx.x >> 6] = v;
  __syncthreads();
  if (threadIdx.x == 0) atomicAdd(out, wsum[0] + wsum[1] + wsum[2] + wsum[3]);
}

extern "C" void kernel_launch(void* const* d_in, const int* in_sizes, int n_in,
                              void* d_out, int out_size, void* d_ws, size_t ws_size,
                              hipStream_t stream) {
  const float* inputs = (const float*)d_in[0];
  const int* labels = (const int*)d_in[1];
  float* out = (float*)d_out;
  float* ws = (float*)d_ws;

  hipMemsetAsync(d_out, 0, sizeof(float), stream);

  float Bq[4], Qq[4];
  for (int m = 0; m < 4; ++m) {
    const float lpv = logf(0.1f + 1e-6f) - logf(powf(0.1f, (float)(5 - m)) + 1e-6f);
    Bq[m] = 0.1f * lpv;
    Qq[m] = Bq[m] * Bq[m];
  }

  dim3 grid(N / 128, N / 128);  // (bj, bi) = 32 x 32
  logratio_phaseA<<<grid, 256, 0, stream>>>(inputs, labels, ws,
                                            Bq[0], Bq[1], Bq[2], Bq[3],
                                            Qq[0], Qq[1], Qq[2], Qq[3]);
  logratio_phaseB<<<N / 256, 256, 0, stream>>>(ws, out, Bq[0], Qq[0]);
}

// Round 4
// 92.457 us; speedup vs baseline: 1.4775x; 1.4775x over previous
//
#include <hip/hip_runtime.h>
#include <math.h>

constexpr int N   = 4096;
constexpr int D   = 128;
constexpr int LDK = D + 8;     // bf16 elems per padded tile row (272 B stride)
constexpr int NT  = 64;        // distinct target classes

typedef __attribute__((ext_vector_type(8))) short short8;
typedef __attribute__((ext_vector_type(4))) float floatx4;

__device__ inline unsigned short f2bf(float f) {
  unsigned u = __builtin_bit_cast(unsigned, f);
  u = (u + 0x7FFFu + ((u >> 16) & 1u)) >> 16;   // RNE
  return (unsigned short)u;
}

// coefTab[t*N + j] = {gB, gQ, g0, e0}; built fresh every call (ws is poisoned).
__global__ __launch_bounds__(256) void build_coef(
    const int* __restrict__ labels, float4* __restrict__ tab,
    float B0, float B1, float B2, float B3,
    float Q0, float Q1, float Q2, float Q3) {
  const int idx = blockIdx.x * 256 + threadIdx.x;  // 0 .. 64*4096-1
  const int t = idx >> 12;
  const int j = idx & (N - 1);
  const int4 L = ((const int4*)labels)[j];
  const bool e0 = (t == L.x), e1 = (t == L.y), e2 = (t == L.z), e3 = (t == L.w);
  const bool n0 = !e3, n1 = e3 && !e2, n2 = e2 && !e1, n3 = e1 && !e0;
  const float g0 = (float)((n0 ? 1 : 0) + (n1 ? 1 : 0) + (n2 ? 1 : 0) + (n3 ? 1 : 0));
  const float gB = (n0 ? B0 : 0.f) + (n1 ? B1 : 0.f) + (n2 ? B2 : 0.f) + (n3 ? B3 : 0.f);
  const float gQ = (n0 ? Q0 : 0.f) + (n1 ? Q1 : 0.f) + (n2 ? Q2 : 0.f) + (n3 ? Q3 : 0.f);
  tab[idx] = make_float4(gB, gQ, g0, e0 ? 1.f : 0.f);
}

// part[i*256 + bj*8 + k], k: 0=c 1=S1 2=S2 3=A 4=B 5=C (6,7 pad, never read)
__global__ __launch_bounds__(256, 2) void logratio_phaseA(
    const float* __restrict__ inputs, const int* __restrict__ labels,
    const float4* __restrict__ tab, float* __restrict__ part) {

  __shared__ __align__(16) char smem[2 * 128 * LDK * 2];  // 69632 B
  unsigned short* As = (unsigned short*)smem;   // [128][LDK]
  unsigned short* Bs = As + 128 * LDK;
  float* Red = (float*)smem;                    // reused post-MFMA: [128][97]

  const int tid = threadIdx.x;
  const int iBase = blockIdx.y * 128;
  const int jBase = blockIdx.x * 128;

  // ---- stage both tiles fp32 -> bf16, coalesced float4 reads ----
#pragma unroll
  for (int p = 0; p < 16; ++p) {
    const int idx = p * 256 + tid;
    const int row = idx >> 5;
    const int cf  = idx & 31;
    const float4 va = *(const float4*)&inputs[(iBase + row) * D + cf * 4];
    uint2 wa;
    wa.x = (unsigned)f2bf(va.x) | ((unsigned)f2bf(va.y) << 16);
    wa.y = (unsigned)f2bf(va.z) | ((unsigned)f2bf(va.w) << 16);
    *(uint2*)&As[row * LDK + cf * 4] = wa;
    const float4 vb = *(const float4*)&inputs[(jBase + row) * D + cf * 4];
    uint2 wb;
    wb.x = (unsigned)f2bf(vb.x) | ((unsigned)f2bf(vb.y) << 16);
    wb.y = (unsigned)f2bf(vb.z) | ((unsigned)f2bf(vb.w) << 16);
    *(uint2*)&Bs[row * LDK + cf * 4] = wb;
  }
  __syncthreads();

  const int w    = tid >> 6;
  const int lane = tid & 63;
  const int lc   = lane & 15;
  const int quad = lane >> 4;

  floatx4 acc[2][8] = {};
  const unsigned short* Abase = As + (w * 32 + lc) * LDK + quad * 8;
  const unsigned short* Bbase = Bs + lc * LDK + quad * 8;

#pragma unroll
  for (int kb = 0; kb < 4; ++kb) {
    short8 af[2], bfr[8];
    af[0] = *(const short8*)(Abase + kb * 32);
    af[1] = *(const short8*)(Abase + 16 * LDK + kb * 32);
#pragma unroll
    for (int tn = 0; tn < 8; ++tn)
      bfr[tn] = *(const short8*)(Bbase + tn * 16 * LDK + kb * 32);
#pragma unroll
    for (int tm = 0; tm < 2; ++tm)
#pragma unroll
      for (int tn = 0; tn < 8; ++tn)
        acc[tm][tn] = __builtin_amdgcn_mfma_f32_16x16x32_bf16(af[tm], bfr[tn], acc[tm][tn], 0, 0, 0);
  }

  __syncthreads();   // tile reads done; smem becomes Red

  // ---- fused epilogue: table-driven, pure load+FMA ----
  const bool diag = (iBase == jBase);
#pragma unroll
  for (int tm = 0; tm < 2; ++tm) {
#pragma unroll
    for (int reg = 0; reg < 4; ++reg) {
      const int row = w * 32 + tm * 16 + quad * 4 + reg;
      const int gi = iBase + row;
      const int ti = labels[gi * 4];
      const float4* tabrow = tab + ti * N + jBase + lc;
      const int dcol = diag ? row : -1;

      float a_c = 0.f, a_s1 = 0.f, a_s2 = 0.f;
      float a_A = 0.f, a_B = 0.f, a_C = 0.f;
#pragma unroll
      for (int tn = 0; tn < 8; ++tn) {
        const float4 cf = tabrow[tn * 16];
        const float ls = __logf(acc[tm][tn][reg] + 1e-6f);
        const float t1 = fmaf(cf.z, ls, cf.x);        // g0·ls + gB
        a_A += cf.z;
        a_B += t1;
        a_C += fmaf(t1 + cf.x, ls, cf.y);             // g0·ls² + 2gB·ls + gQ
        const float f = (tn * 16 + lc == dcol) ? 0.f : cf.w;
        const float fls = f * ls;
        a_c += f;
        a_s1 += fls;
        a_s2 = fmaf(fls, ls, a_s2);
      }
      float* dst = Red + row * 97 + lc * 6;
      dst[0] = a_c;  dst[1] = a_s1; dst[2] = a_s2;
      dst[3] = a_A;  dst[4] = a_B;  dst[5] = a_C;
    }
  }
  __syncthreads();

  // ---- per-row reduction over 16 lane-partials, non-atomic block partials ----
  if (tid < 128) {
    const int gi = iBase + tid;
    const float* src = Red + tid * 97;
    float s0 = 0.f, s1 = 0.f, s2 = 0.f, s3 = 0.f, s4 = 0.f, s5 = 0.f;
#pragma unroll
    for (int l = 0; l < 16; ++l) {
      s0 += src[l * 6 + 0]; s1 += src[l * 6 + 1]; s2 += src[l * 6 + 2];
      s3 += src[l * 6 + 3]; s4 += src[l * 6 + 4]; s5 += src[l * 6 + 5];
    }
    float* dst = part + (size_t)gi * 256 + blockIdx.x * 8;
    *(float4*)dst       = make_float4(s0, s1, s2, s3);
    *(float2*)(dst + 4) = make_float2(s4, s5);
  }
}

__global__ __launch_bounds__(256) void logratio_phaseB(
    const float* __restrict__ part, float* __restrict__ out) {
  const int i = blockIdx.x * 256 + threadIdx.x;
  const float* p = part + (size_t)i * 256;
  float c = 0.f, S1 = 0.f, S2 = 0.f, A = 0.f, B = 0.f, C = 0.f;
#pragma unroll 8
  for (int b = 0; b < 32; ++b) {
    const float4 x = *(const float4*)(p + b * 8);
    const float2 y = *(const float2*)(p + b * 8 + 4);
    c += x.x; S1 += x.y; S2 += x.z; A += x.w; B += y.x; C += y.y;
  }
  float v = S2 * A - 2.f * S1 * B + c * C;
#pragma unroll
  for (int m = 32; m >= 1; m >>= 1) v += __shfl_xor(v, m, 64);
  __shared__ float wsum[4];
  if ((threadIdx.x & 63) == 0) wsum[threadIdx.x >> 6] = v;
  __syncthreads();
  if (threadIdx.x == 0) atomicAdd(out, wsum[0] + wsum[1] + wsum[2] + wsum[3]);
}

extern "C" void kernel_launch(void* const* d_in, const int* in_sizes, int n_in,
                              void* d_out, int out_size, void* d_ws, size_t ws_size,
                              hipStream_t stream) {
  const float* inputs = (const float*)d_in[0];
  const int* labels = (const int*)d_in[1];
  float* out = (float*)d_out;
  float4* tab = (float4*)d_ws;                       // 64*4096*16 B = 4 MB
  float* part = (float*)d_ws + (NT * N * 4);         // after table: 4096*256*4 B = 4 MB

  hipMemsetAsync(d_out, 0, sizeof(float), stream);

  float Bq[4], Qq[4];
  for (int m = 0; m < 4; ++m) {
    const float lpv = logf(0.1f + 1e-6f) - logf(powf(0.1f, (float)(5 - m)) + 1e-6f);
    Bq[m] = 0.1f * lpv;
    Qq[m] = Bq[m] * Bq[m];
  }

  build_coef<<<NT * N / 256, 256, 0, stream>>>(labels, tab,
                                               Bq[0], Bq[1], Bq[2], Bq[3],
                                               Qq[0], Qq[1], Qq[2], Qq[3]);
  dim3 grid(N / 128, N / 128);  // (bj, bi) = 32 x 32
  logratio_phaseA<<<grid, 256, 0, stream>>>(inputs, labels, tab, part);
  logratio_phaseB<<<N / 256, 256, 0, stream>>>(part, out);
}

// Round 5
// 83.908 us; speedup vs baseline: 1.6280x; 1.1019x over previous
//
#include <hip/hip_runtime.h>
#include <math.h>

constexpr int N  = 4096;
constexpr int D  = 128;
constexpr int NT = 64;

// ws layout (bytes):
//   tab   : [0, 4 MB)              float4 tab[64][4096] = {gB, gQ, g0, e0}
//   xbf   : [4 MB, +1 MB)          bf16 X image, 4096 rows x 256 B, XOR-swizzled
//   acc6  : [5 MB, +96 KB)         float acc6[6][4096]
//   lsdiag: [5 MB + 96 KB, +16 KB) float lsdiag[4096]
constexpr size_t TAB_OFF = 0;
constexpr size_t XBF_OFF = (size_t)4 << 20;
constexpr size_t ACC_OFF = (size_t)5 << 20;
constexpr size_t LSD_OFF = ((size_t)5 << 20) + ((size_t)96 << 10);

typedef __attribute__((ext_vector_type(8))) short short8;
typedef __attribute__((ext_vector_type(4))) float floatx4;
typedef __attribute__((address_space(1))) unsigned int gu32;
typedef __attribute__((address_space(3))) unsigned int lu32;

__device__ inline unsigned f2bf(float f) {
  unsigned u = __builtin_bit_cast(unsigned, f);
  return (u + 0x7FFFu + ((u >> 16) & 1u)) >> 16;   // RNE
}

// ---- K1: build coef table + convert/swizzle X to bf16 + diag logs + zero accums/out ----
__global__ __launch_bounds__(256) void k1_prep(
    const float* __restrict__ X, const int* __restrict__ labels,
    char* __restrict__ ws, float* __restrict__ out,
    float B0, float B1, float B2, float B3,
    float Q0, float Q1, float Q2, float Q3) {
  const int b = blockIdx.x, t = threadIdx.x;
  if (b < 1024) {
    const int idx = b * 256 + t;                 // 0 .. 64*4096-1
    const int tt = idx >> 12;
    const int j  = idx & (N - 1);
    const int4 L = ((const int4*)labels)[j];
    const bool e0 = (tt == L.x), e1 = (tt == L.y), e2 = (tt == L.z), e3 = (tt == L.w);
    const bool n0 = !e3, n1 = e3 && !e2, n2 = e2 && !e1, n3 = e1 && !e0;
    const float g0 = (float)((n0 ? 1 : 0) + (n1 ? 1 : 0) + (n2 ? 1 : 0) + (n3 ? 1 : 0));
    const float gB = (n0 ? B0 : 0.f) + (n1 ? B1 : 0.f) + (n2 ? B2 : 0.f) + (n3 ? B3 : 0.f);
    const float gQ = (n0 ? Q0 : 0.f) + (n1 ? Q1 : 0.f) + (n2 ? Q2 : 0.f) + (n3 ? Q3 : 0.f);
    ((float4*)(ws + TAB_OFF))[idx] = make_float4(gB, gQ, g0, e0 ? 1.f : 0.f);
    if (idx < 6 * N) ((float*)(ws + ACC_OFF))[idx] = 0.f;
  } else if (b < 1280) {
    const int task = (b - 1024) * 256 + t;       // 0 .. 65535
    const int r   = task >> 4;
    const int blk = task & 15;
    const float4 x0 = *(const float4*)&X[r * D + blk * 8];
    const float4 x1 = *(const float4*)&X[r * D + blk * 8 + 4];
    uint4 wv;
    wv.x = f2bf(x0.x) | (f2bf(x0.y) << 16);
    wv.y = f2bf(x0.z) | (f2bf(x0.w) << 16);
    wv.z = f2bf(x1.x) | (f2bf(x1.y) << 16);
    wv.w = f2bf(x1.z) | (f2bf(x1.w) << 16);
    *(uint4*)(ws + XBF_OFF + (size_t)r * 256 + ((blk ^ (r & 15)) * 16)) = wv;
  } else {
    const int i = (b - 1280) * 256 + t;          // 0 .. 4095
    const float* xr = X + i * D;
    float s = 0.f;
#pragma unroll
    for (int c = 0; c < 32; ++c) {
      const float4 v = ((const float4*)xr)[c];
      s += v.x * v.x + v.y * v.y + v.z * v.z + v.w * v.w;
    }
    ((float*)(ws + LSD_OFF))[i] = __logf(s + 1e-6f);
    if (b == 1295 && t == 0) out[0] = 0.f;
  }
}

// ---- phaseA: MFMA sim tile + table-driven epilogue; global_load_lds staging ----
__global__ __launch_bounds__(512, 4) void logratio_phaseA(
    const char* __restrict__ ws_ro, const int* __restrict__ labels,
    float* acc6) {

  __shared__ __align__(16) char smem[65536];   // B tile [0,32K) + A tile [32K,64K); Red overlays after

  const int tid  = threadIdx.x;
  const int w    = tid >> 6;     // 8 waves
  const int lane = tid & 63;
  const int lc   = lane & 15;
  const int quad = lane >> 4;
  const int jBase = blockIdx.x * 128;
  const int iBase = blockIdx.y * 128;

  const char* xbf = ws_ro + XBF_OFF;
  const char* gB_ = xbf + (size_t)jBase * 256 + w * 4096 + lane * 16;
  const char* gA_ = xbf + (size_t)iBase * 256 + w * 4096 + lane * 16;
#pragma unroll
  for (int c = 0; c < 4; ++c) {
    __builtin_amdgcn_global_load_lds((const gu32*)(gB_ + c * 1024),
                                     (lu32*)(smem + w * 4096 + c * 1024), 16, 0, 0);
    __builtin_amdgcn_global_load_lds((const gu32*)(gA_ + c * 1024),
                                     (lu32*)(smem + 32768 + w * 4096 + c * 1024), 16, 0, 0);
  }

  // prefetch row targets while loads fly
  int tis[4];
#pragma unroll
  for (int reg = 0; reg < 4; ++reg)
    tis[reg] = labels[(iBase + w * 16 + quad * 4 + reg) * 4];

  __syncthreads();

  // MFMA: wave w computes C rows w*16..w*16+15 x all 128 cols
  floatx4 acc[8] = {};
  const char* Abase = smem + 32768 + (w * 16 + lc) * 256;
#pragma unroll
  for (int kb = 0; kb < 4; ++kb) {
    const int pb = ((kb * 4 + quad) ^ lc) * 16;   // XOR-swizzled 16B block
    const short8 af = *(const short8*)(Abase + pb);
    short8 bfr[8];
#pragma unroll
    for (int tn = 0; tn < 8; ++tn)
      bfr[tn] = *(const short8*)(smem + (tn * 16 + lc) * 256 + pb);
#pragma unroll
    for (int tn = 0; tn < 8; ++tn)
      acc[tn] = __builtin_amdgcn_mfma_f32_16x16x32_bf16(af, bfr[tn], acc[tn], 0, 0, 0);
  }

  __syncthreads();              // all tile reads done; smem becomes Red
  float* Red = (float*)smem;    // [128][97]

  const float4* tab = (const float4*)(ws_ro + TAB_OFF);
#pragma unroll
  for (int reg = 0; reg < 4; ++reg) {
    const int row = w * 16 + quad * 4 + reg;
    const float4* trow = tab + (size_t)tis[reg] * N + jBase + lc;

    float a_c = 0.f, a_s1 = 0.f, a_s2 = 0.f;
    float a_A = 0.f, a_B = 0.f, a_C = 0.f;
#pragma unroll
    for (int tn = 0; tn < 8; ++tn) {
      const float4 cf = trow[tn * 16];
      const float ls = __logf(acc[tn][reg] + 1e-6f);
      const float t1 = fmaf(cf.z, ls, cf.x);        // g0*ls + gB
      a_A += cf.z;
      a_B += t1;
      a_C += fmaf(t1 + cf.x, ls, cf.y);             // g0*ls^2 + 2gB*ls + gQ
      const float fls = cf.w * ls;                  // pos weight (diag fixed in phaseB)
      a_c += cf.w;
      a_s1 += fls;
      a_s2 = fmaf(fls, ls, a_s2);
    }
    float* dst = Red + row * 97 + lc * 6;
    dst[0] = a_c;  dst[1] = a_s1; dst[2] = a_s2;
    dst[3] = a_A;  dst[4] = a_B;  dst[5] = a_C;
  }
  __syncthreads();

  if (tid < 128) {
    const int gi = iBase + tid;
    const float* src = Red + tid * 97;
    float s0 = 0.f, s1 = 0.f, s2 = 0.f, s3 = 0.f, s4 = 0.f, s5 = 0.f;
#pragma unroll
    for (int l = 0; l < 16; ++l) {
      s0 += src[l * 6 + 0]; s1 += src[l * 6 + 1]; s2 += src[l * 6 + 2];
      s3 += src[l * 6 + 3]; s4 += src[l * 6 + 4]; s5 += src[l * 6 + 5];
    }
    atomicAdd(&acc6[0 * N + gi], s0);
    atomicAdd(&acc6[1 * N + gi], s1);
    atomicAdd(&acc6[2 * N + gi], s2);
    atomicAdd(&acc6[3 * N + gi], s3);
    atomicAdd(&acc6[4 * N + gi], s4);
    atomicAdd(&acc6[5 * N + gi], s5);
  }
}

// ---- phaseB: diag correction + final combine ----
__global__ __launch_bounds__(256) void logratio_phaseB(
    const char* __restrict__ ws_ro, float* out) {
  const int i = blockIdx.x * 256 + threadIdx.x;
  const float* acc6 = (const float*)(ws_ro + ACC_OFF);
  float c  = acc6[0 * N + i];
  float S1 = acc6[1 * N + i];
  float S2 = acc6[2 * N + i];
  const float A = acc6[3 * N + i];
  const float B = acc6[4 * N + i];
  const float C = acc6[5 * N + i];
  const float lsd = ((const float*)(ws_ro + LSD_OFF))[i];
  c  -= 1.f;                 // pos diagonal always matches (t_i == labels[i,0])
  S1 -= lsd;
  S2 -= lsd * lsd;
  float v = S2 * A - 2.f * S1 * B + c * C;
#pragma unroll
  for (int m = 32; m >= 1; m >>= 1) v += __shfl_xor(v, m, 64);
  __shared__ float wsum[4];
  if ((threadIdx.x & 63) == 0) wsum[threadIdx.x >> 6] = v;
  __syncthreads();
  if (threadIdx.x == 0) atomicAdd(out, wsum[0] + wsum[1] + wsum[2] + wsum[3]);
}

extern "C" void kernel_launch(void* const* d_in, const int* in_sizes, int n_in,
                              void* d_out, int out_size, void* d_ws, size_t ws_size,
                              hipStream_t stream) {
  const float* inputs = (const float*)d_in[0];
  const int* labels = (const int*)d_in[1];
  float* out = (float*)d_out;
  char* ws = (char*)d_ws;

  float Bq[4], Qq[4];
  for (int m = 0; m < 4; ++m) {
    const float lpv = logf(0.1f + 1e-6f) - logf(powf(0.1f, (float)(5 - m)) + 1e-6f);
    Bq[m] = 0.1f * lpv;
    Qq[m] = Bq[m] * Bq[m];
  }

  k1_prep<<<1296, 256, 0, stream>>>(inputs, labels, ws, out,
                                    Bq[0], Bq[1], Bq[2], Bq[3],
                                    Qq[0], Qq[1], Qq[2], Qq[3]);
  dim3 grid(N / 128, N / 128);  // 32 x 32
  logratio_phaseA<<<grid, 512, 0, stream>>>(ws, labels, (float*)(ws + ACC_OFF));
  logratio_phaseB<<<N / 256, 256, 0, stream>>>(ws, out);
}